// Round 3
// baseline (844.965 us; speedup 1.0000x reference)
//
#include <hip/hip_runtime.h>

#define B_ 8
#define N_ 256
#define D_ 512
#define TI 8   // query rows per block

// ---------- Kernel 0: transpose k[b][j][d] -> kT[b][d][j] ----------
__global__ __launch_bounds__(256)
void transpose_k(const float* __restrict__ k, float* __restrict__ kT)
{
    __shared__ float tile[32][33];
    const int dt = blockIdx.x * 32;
    const int jt = blockIdx.y * 32;
    const int b  = blockIdx.z;
    const int tx = threadIdx.x;   // 0..31
    const int ty = threadIdx.y;   // 0..7

    const float* __restrict__ src = k  + ((size_t)b * N_) * D_;
    float* __restrict__       dst = kT + ((size_t)b * D_) * N_;

    #pragma unroll
    for (int r = 0; r < 4; ++r) {
        const int jj = ty * 4 + r;
        tile[jj][tx] = src[(size_t)(jt + jj) * D_ + dt + tx];
    }
    __syncthreads();
    #pragma unroll
    for (int r = 0; r < 4; ++r) {
        const int dd = ty * 4 + r;
        dst[(size_t)(dt + dd) * N_ + jt + tx] = tile[tx][dd];
    }
}

// ---------- Main kernel: TI=8, 1024 threads (16 waves), grid = 256 ----------
__global__ __launch_bounds__(1024, 4)
void manh_attn_v3(const float* __restrict__ q,
                  const float* __restrict__ kT,
                  const float* __restrict__ v,
                  float* __restrict__ out)
{
    __shared__ float s_q[TI * D_];      // 16 KB: q rows for this tile
    __shared__ float s_part[16 * 512];  // 32 KB: reduction scratch (reused)
    __shared__ float s_w[TI * N_];      // 8 KB: scores -> attn weights

    const int t  = threadIdx.x;
    const int b  = blockIdx.x >> 5;        // 32 i-tiles per batch
    const int i0 = (blockIdx.x & 31) * TI;

    // ---- stage q[b][i0..i0+7][*] into LDS (coalesced float4) ----
    {
        const int r = t >> 7;              // 0..7
        const int d = (t & 127) * 4;       // 0..508
        *(float4*)&s_q[r * D_ + d] =
            *(const float4*)(q + ((size_t)(b * N_ + i0 + r)) * D_ + d);
    }
    __syncthreads();

    // ---- Phase A: partial L1 distances ----
    // thread (jq = j-quad 0..63, h = d-group 0..15, 32 d each)
    const int jq = t & 63;
    const int h  = t >> 6;                 // == wave id, wave-uniform

    float acc[TI][4];
    #pragma unroll
    for (int r = 0; r < TI; ++r) {
        acc[r][0] = 0.f; acc[r][1] = 0.f; acc[r][2] = 0.f; acc[r][3] = 0.f;
    }

    const float* __restrict__ kbase =
        kT + (size_t)b * D_ * N_ + (size_t)(h * 32) * N_ + jq * 4;

    #pragma unroll
    for (int db = 0; db < 8; ++db) {       // 4 d's per step
        const float* kp = kbase + (size_t)(db * 4) * N_;
        const float4 k0 = *(const float4*)(kp);
        const float4 k1 = *(const float4*)(kp + N_);
        const float4 k2 = *(const float4*)(kp + 2 * N_);
        const float4 k3 = *(const float4*)(kp + 3 * N_);
        const int dblk = h * 32 + db * 4;
        #pragma unroll
        for (int r = 0; r < TI; ++r) {
            const float4 q4 = *(const float4*)&s_q[r * D_ + dblk];  // uniform broadcast
            acc[r][0] += (fabsf(q4.x - k0.x) + fabsf(q4.y - k1.x)) +
                         (fabsf(q4.z - k2.x) + fabsf(q4.w - k3.x));
            acc[r][1] += (fabsf(q4.x - k0.y) + fabsf(q4.y - k1.y)) +
                         (fabsf(q4.z - k2.y) + fabsf(q4.w - k3.y));
            acc[r][2] += (fabsf(q4.x - k0.z) + fabsf(q4.y - k1.z)) +
                         (fabsf(q4.z - k2.z) + fabsf(q4.w - k3.z));
            acc[r][3] += (fabsf(q4.x - k0.w) + fabsf(q4.y - k1.w)) +
                         (fabsf(q4.z - k2.w) + fabsf(q4.w - k3.w));
        }
    }

    // ---- reduce 16 d-groups -> scores, in 2-row chunks ----
    #pragma unroll
    for (int rc = 0; rc < 4; ++rc) {
        __syncthreads();
        *(float4*)&s_part[h * 512 + jq * 4] =
            make_float4(acc[2 * rc][0], acc[2 * rc][1], acc[2 * rc][2], acc[2 * rc][3]);
        *(float4*)&s_part[h * 512 + 256 + jq * 4] =
            make_float4(acc[2 * rc + 1][0], acc[2 * rc + 1][1], acc[2 * rc + 1][2], acc[2 * rc + 1][3]);
        __syncthreads();
        if (t < 512) {
            const int rl = t >> 8;         // 0..1
            const int j  = t & 255;
            float s = 0.f;
            #pragma unroll
            for (int hh = 0; hh < 16; ++hh) s += s_part[hh * 512 + rl * 256 + j];
            s_w[(2 * rc + rl) * N_ + j] = -s;
        }
    }
    __syncthreads();

    // ---- softmax: wave w handles row w (waves 8..15 idle briefly) ----
    if (h < TI) {
        const int l = t & 63;
        float* row = &s_w[h * N_];
        float v0 = row[l];
        float v1 = row[l + 64];
        float v2 = row[l + 128];
        float v3 = row[l + 192];
        float m = fmaxf(fmaxf(v0, v1), fmaxf(v2, v3));
        #pragma unroll
        for (int off = 32; off; off >>= 1) m = fmaxf(m, __shfl_xor(m, off));
        const float c = 1.4426950408889634f;
        float e0 = exp2f((v0 - m) * c);
        float e1 = exp2f((v1 - m) * c);
        float e2 = exp2f((v2 - m) * c);
        float e3 = exp2f((v3 - m) * c);
        float s = (e0 + e1) + (e2 + e3);
        #pragma unroll
        for (int off = 32; off; off >>= 1) s += __shfl_xor(s, off);
        const float r = 1.0f / s;
        row[l]       = e0 * r;
        row[l + 64]  = e1 * r;
        row[l + 128] = e2 * r;
        row[l + 192] = e3 * r;
    }
    __syncthreads();

    // ---- Phase C: out = attn @ v ----
    // thread (dq = d-quad 0..127, jh = j-group 0..7, 32 j each), all 8 rows
    const int dq = t & 127;
    const int jh = t >> 7;

    float4 oacc[TI];
    #pragma unroll
    for (int r = 0; r < TI; ++r) oacc[r] = make_float4(0.f, 0.f, 0.f, 0.f);

    const float* __restrict__ vb = v + (size_t)b * N_ * D_ + dq * 4;

    #pragma unroll
    for (int jc = 0; jc < 8; ++jc) {       // 4 j's per step
        const int j0 = jh * 32 + jc * 4;
        const float4 v0 = *(const float4*)(vb + (size_t)(j0 + 0) * D_);
        const float4 v1 = *(const float4*)(vb + (size_t)(j0 + 1) * D_);
        const float4 v2 = *(const float4*)(vb + (size_t)(j0 + 2) * D_);
        const float4 v3 = *(const float4*)(vb + (size_t)(j0 + 3) * D_);
        #pragma unroll
        for (int r = 0; r < TI; ++r) {
            const float4 w4 = *(const float4*)&s_w[r * N_ + j0];   // uniform broadcast
            oacc[r].x += w4.x * v0.x + w4.y * v1.x + w4.z * v2.x + w4.w * v3.x;
            oacc[r].y += w4.x * v0.y + w4.y * v1.y + w4.z * v2.y + w4.w * v3.y;
            oacc[r].z += w4.x * v0.z + w4.y * v1.z + w4.z * v2.z + w4.w * v3.z;
            oacc[r].w += w4.x * v0.w + w4.y * v1.w + w4.z * v2.w + w4.w * v3.w;
        }
    }

    // ---- reduce 8 j-groups -> out, in 2-row chunks ----
    #pragma unroll
    for (int rc = 0; rc < 4; ++rc) {
        __syncthreads();
        *(float4*)&s_part[jh * 1024 + dq * 4]       = oacc[2 * rc];
        *(float4*)&s_part[jh * 1024 + 512 + dq * 4] = oacc[2 * rc + 1];
        __syncthreads();
        {
            const int rl = t >> 9;         // 0..1
            const int d  = t & 511;
            float s = 0.f;
            #pragma unroll
            for (int g = 0; g < 8; ++g) s += s_part[g * 1024 + rl * 512 + d];
            out[((size_t)(b * N_ + i0 + 2 * rc + rl)) * D_ + d] = s;
        }
    }
}

// ---------- Fallback (round-1 kernel, used if ws too small) ----------
__global__ __launch_bounds__(256, 2)
void manh_attn_legacy(const float* __restrict__ q,
                      const float* __restrict__ k,
                      const float* __restrict__ v,
                      float* __restrict__ out)
{
    __shared__ float s_mat[4][N_];
    const int t   = threadIdx.x;
    const int bid = blockIdx.x;
    const int b   = bid >> 6;
    const int i0  = (bid & 63) * 4;

    const float* __restrict__ krow  = k + ((size_t)(b * N_ + t)) * D_;
    const float* __restrict__ qbase = q + ((size_t)(b * N_ + i0)) * D_;

    float acc0 = 0.f, acc1 = 0.f, acc2 = 0.f, acc3 = 0.f;
    #pragma unroll 4
    for (int d = 0; d < D_; d += 4) {
        const float4 kv = *(const float4*)(krow + d);
        const float4 q0 = *(const float4*)(qbase + d);
        const float4 q1 = *(const float4*)(qbase + D_ + d);
        const float4 q2 = *(const float4*)(qbase + 2 * D_ + d);
        const float4 q3 = *(const float4*)(qbase + 3 * D_ + d);
        acc0 += (fabsf(q0.x - kv.x) + fabsf(q0.y - kv.y)) + (fabsf(q0.z - kv.z) + fabsf(q0.w - kv.w));
        acc1 += (fabsf(q1.x - kv.x) + fabsf(q1.y - kv.y)) + (fabsf(q1.z - kv.z) + fabsf(q1.w - kv.w));
        acc2 += (fabsf(q2.x - kv.x) + fabsf(q2.y - kv.y)) + (fabsf(q2.z - kv.z) + fabsf(q2.w - kv.w));
        acc3 += (fabsf(q3.x - kv.x) + fabsf(q3.y - kv.y)) + (fabsf(q3.z - kv.z) + fabsf(q3.w - kv.w));
    }
    s_mat[0][t] = -acc0; s_mat[1][t] = -acc1; s_mat[2][t] = -acc2; s_mat[3][t] = -acc3;
    __syncthreads();
    {
        const int w = t >> 6;
        const int l = t & 63;
        float v0 = s_mat[w][l], v1 = s_mat[w][l + 64], v2 = s_mat[w][l + 128], v3 = s_mat[w][l + 192];
        float m = fmaxf(fmaxf(v0, v1), fmaxf(v2, v3));
        #pragma unroll
        for (int off = 32; off; off >>= 1) m = fmaxf(m, __shfl_xor(m, off));
        const float c = 1.4426950408889634f;
        float e0 = exp2f((v0 - m) * c), e1 = exp2f((v1 - m) * c);
        float e2 = exp2f((v2 - m) * c), e3 = exp2f((v3 - m) * c);
        float s = (e0 + e1) + (e2 + e3);
        #pragma unroll
        for (int off = 32; off; off >>= 1) s += __shfl_xor(s, off);
        const float r = 1.0f / s;
        s_mat[w][l] = e0 * r; s_mat[w][l + 64] = e1 * r;
        s_mat[w][l + 128] = e2 * r; s_mat[w][l + 192] = e3 * r;
    }
    __syncthreads();
    const int ig = t >> 7;
    const int d0 = (t & 127) * 4;
    const float* __restrict__ vbase = v + ((size_t)b * N_) * D_ + d0;
    const float* __restrict__ wr0 = &s_mat[2 * ig][0];
    const float* __restrict__ wr1 = &s_mat[2 * ig + 1][0];
    float4 a0 = make_float4(0.f, 0.f, 0.f, 0.f);
    float4 a1 = make_float4(0.f, 0.f, 0.f, 0.f);
#define PV_STEP(W0, W1, VV)                                     \
    a0.x += (W0) * (VV).x; a0.y += (W0) * (VV).y;               \
    a0.z += (W0) * (VV).z; a0.w += (W0) * (VV).w;               \
    a1.x += (W1) * (VV).x; a1.y += (W1) * (VV).y;               \
    a1.z += (W1) * (VV).z; a1.w += (W1) * (VV).w;
    #pragma unroll 2
    for (int j = 0; j < N_; j += 4) {
        const float4 w0 = *(const float4*)(wr0 + j);
        const float4 w1 = *(const float4*)(wr1 + j);
        const float4 vv0 = *(const float4*)(vbase + (size_t)(j + 0) * D_);
        const float4 vv1 = *(const float4*)(vbase + (size_t)(j + 1) * D_);
        const float4 vv2 = *(const float4*)(vbase + (size_t)(j + 2) * D_);
        const float4 vv3 = *(const float4*)(vbase + (size_t)(j + 3) * D_);
        PV_STEP(w0.x, w1.x, vv0)
        PV_STEP(w0.y, w1.y, vv1)
        PV_STEP(w0.z, w1.z, vv2)
        PV_STEP(w0.w, w1.w, vv3)
    }
#undef PV_STEP
    float* op = out + ((size_t)(b * N_ + i0 + 2 * ig)) * D_ + d0;
    *(float4*)op        = a0;
    *(float4*)(op + D_) = a1;
}

extern "C" void kernel_launch(void* const* d_in, const int* in_sizes, int n_in,
                              void* d_out, int out_size, void* d_ws, size_t ws_size,
                              hipStream_t stream)
{
    const float* q = (const float*)d_in[0];
    const float* k = (const float*)d_in[1];
    const float* v = (const float*)d_in[2];
    float* out = (float*)d_out;

    const size_t kT_bytes = (size_t)B_ * N_ * D_ * sizeof(float);
    if (ws_size >= kT_bytes) {
        float* kT = (float*)d_ws;
        transpose_k<<<dim3(D_ / 32, N_ / 32, B_), dim3(32, 8), 0, stream>>>(k, kT);
        manh_attn_v3<<<dim3(B_ * (N_ / TI)), dim3(1024), 0, stream>>>(q, kT, v, out);
    } else {
        manh_attn_legacy<<<dim3(B_ * 64), dim3(256), 0, stream>>>(q, k, v, out);
    }
}

// Round 4
// 51.663 us; speedup vs baseline: 16.3553x; 16.3553x over previous
//
#include <hip/hip_runtime.h>

#define B_ 8
#define N_ 256
#define D_ 512
#define TI 8   // query rows per block

// ---------- Kernel 0: transpose k[b][j][d] -> kT[b][d][j] ----------
__global__ __launch_bounds__(256)
void transpose_k(const float* __restrict__ k, float* __restrict__ kT)
{
    __shared__ float tile[32][33];
    const int dt = blockIdx.x * 32;
    const int jt = blockIdx.y * 32;
    const int b  = blockIdx.z;
    const int tx = threadIdx.x;   // 0..31
    const int ty = threadIdx.y;   // 0..7

    const float* __restrict__ src = k  + ((size_t)b * N_) * D_;
    float* __restrict__       dst = kT + ((size_t)b * D_) * N_;

    #pragma unroll
    for (int r = 0; r < 4; ++r) {
        const int jj = ty * 4 + r;
        tile[jj][tx] = src[(size_t)(jt + jj) * D_ + dt + tx];
    }
    __syncthreads();
    #pragma unroll
    for (int r = 0; r < 4; ++r) {
        const int dd = ty * 4 + r;
        dst[(size_t)(dt + dd) * N_ + jt + tx] = tile[tx][dd];
    }
}

// ---------- Main kernel: TI=8, 512 threads (8 waves), grid = 256 ----------
// Wave w: d-quarter (w>>1), row-group (w&1) -> 4 rows. acc = 16 VGPR.
__global__ __launch_bounds__(512)
void manh_attn_v4(const float* __restrict__ q,
                  const float* __restrict__ kT,
                  const float* __restrict__ v,
                  float* __restrict__ out)
{
    __shared__ float s_q[TI * D_];       // 16 KB
    __shared__ float s_part[8 * 1024];   // 32 KB: 8 waves x 4 rows x 256 j
    __shared__ float s_w[TI * N_];       // 8 KB

    const int t  = threadIdx.x;
    const int b  = blockIdx.x >> 5;         // N_/TI = 32 i-tiles per batch
    const int i0 = (blockIdx.x & 31) * TI;

    // ---- stage q tile (8 rows x 512) into LDS, coalesced float4 ----
    {
        const float* __restrict__ qsrc = q + ((size_t)(b * N_ + i0)) * D_;
        *(float4*)&s_q[4 * t]         = *(const float4*)(qsrc + 4 * t);
        *(float4*)&s_q[4 * (t + 512)] = *(const float4*)(qsrc + 4 * (t + 512));
    }
    __syncthreads();

    const int lane = t & 63;
    const int w    = t >> 6;       // 0..7
    const int dh   = w >> 1;       // d-quarter 0..3
    const int rg   = w & 1;        // row-group: rows rg*4 .. rg*4+3
    const int dlo  = dh * 128;

    // ---- Phase A: partial L1 distances ----
    float4 acc0 = make_float4(0.f,0.f,0.f,0.f);
    float4 acc1 = make_float4(0.f,0.f,0.f,0.f);
    float4 acc2 = make_float4(0.f,0.f,0.f,0.f);
    float4 acc3 = make_float4(0.f,0.f,0.f,0.f);

    const float* __restrict__ kbase =
        kT + (size_t)b * D_ * N_ + (size_t)dlo * N_ + lane * 4;
    const float* __restrict__ qrow0 = &s_q[(rg * 4 + 0) * D_ + dlo];
    const float* __restrict__ qrow1 = &s_q[(rg * 4 + 1) * D_ + dlo];
    const float* __restrict__ qrow2 = &s_q[(rg * 4 + 2) * D_ + dlo];
    const float* __restrict__ qrow3 = &s_q[(rg * 4 + 3) * D_ + dlo];

#define ACC_ROW(A, QP)                                                         \
    {                                                                          \
        const float4 q4 = *(const float4*)((QP) + dd);                         \
        A.x += (fabsf(q4.x - k0.x) + fabsf(q4.y - k1.x)) +                     \
               (fabsf(q4.z - k2.x) + fabsf(q4.w - k3.x));                      \
        A.y += (fabsf(q4.x - k0.y) + fabsf(q4.y - k1.y)) +                     \
               (fabsf(q4.z - k2.y) + fabsf(q4.w - k3.y));                      \
        A.z += (fabsf(q4.x - k0.z) + fabsf(q4.y - k1.z)) +                     \
               (fabsf(q4.z - k2.z) + fabsf(q4.w - k3.z));                      \
        A.w += (fabsf(q4.x - k0.w) + fabsf(q4.y - k1.w)) +                     \
               (fabsf(q4.z - k2.w) + fabsf(q4.w - k3.w));                      \
    }

    #pragma unroll 2
    for (int dd = 0; dd < 128; dd += 4) {
        const float* kp = kbase + (size_t)dd * N_;
        const float4 k0 = *(const float4*)(kp);
        const float4 k1 = *(const float4*)(kp + N_);
        const float4 k2 = *(const float4*)(kp + 2 * N_);
        const float4 k3 = *(const float4*)(kp + 3 * N_);
        ACC_ROW(acc0, qrow0)
        ACC_ROW(acc1, qrow1)
        ACC_ROW(acc2, qrow2)
        ACC_ROW(acc3, qrow3)
    }
#undef ACC_ROW

    // ---- dump partials (one shot, nothing stays live) ----
    *(float4*)&s_part[w * 1024 +   0 + lane * 4] = acc0;
    *(float4*)&s_part[w * 1024 + 256 + lane * 4] = acc1;
    *(float4*)&s_part[w * 1024 + 512 + lane * 4] = acc2;
    *(float4*)&s_part[w * 1024 + 768 + lane * 4] = acc3;
    __syncthreads();

    // ---- reduce 4 d-partials -> scores ----
    // row r partials live in waves w = 2h + (r>>2), slot (r&3)
    #pragma unroll
    for (int i = 0; i < 4; ++i) {
        const int e  = t + 512 * i;     // 0..2047
        const int r  = e >> 8;          // 0..7
        const int j  = e & 255;
        const int wb = (r >> 2);        // 0 or 1
        const int sl = (r & 3) * 256 + j;
        const float s = (s_part[(wb + 0) * 1024 + sl] + s_part[(wb + 2) * 1024 + sl]) +
                        (s_part[(wb + 4) * 1024 + sl] + s_part[(wb + 6) * 1024 + sl]);
        s_w[r * N_ + j] = -s;
    }
    __syncthreads();

    // ---- softmax: wave w handles row w ----
    {
        float* row = &s_w[w * N_];
        float v0 = row[lane];
        float v1 = row[lane + 64];
        float v2 = row[lane + 128];
        float v3 = row[lane + 192];
        float m = fmaxf(fmaxf(v0, v1), fmaxf(v2, v3));
        #pragma unroll
        for (int off = 32; off; off >>= 1) m = fmaxf(m, __shfl_xor(m, off));
        const float c = 1.4426950408889634f;
        float e0 = exp2f((v0 - m) * c);
        float e1 = exp2f((v1 - m) * c);
        float e2 = exp2f((v2 - m) * c);
        float e3 = exp2f((v3 - m) * c);
        float s = (e0 + e1) + (e2 + e3);
        #pragma unroll
        for (int off = 32; off; off >>= 1) s += __shfl_xor(s, off);
        const float r = 1.0f / s;
        row[lane]       = e0 * r;
        row[lane + 64]  = e1 * r;
        row[lane + 128] = e2 * r;
        row[lane + 192] = e3 * r;
    }
    __syncthreads();

    // ---- Phase C: out = attn @ v ----
    // thread: d-quad dq = t&127, row pair rp = t>>7 -> rows {2rp, 2rp+1}
    const int dq = t & 127;
    const int rp = t >> 7;
    const float* __restrict__ vb  = v + (size_t)b * N_ * D_ + dq * 4;
    const float* __restrict__ wr0 = &s_w[(2 * rp) * N_];
    const float* __restrict__ wr1 = &s_w[(2 * rp + 1) * N_];

    float4 a0 = make_float4(0.f,0.f,0.f,0.f);
    float4 a1 = make_float4(0.f,0.f,0.f,0.f);

#define PV_STEP(W0, W1, VV)                                     \
    a0.x += (W0) * (VV).x; a0.y += (W0) * (VV).y;               \
    a0.z += (W0) * (VV).z; a0.w += (W0) * (VV).w;               \
    a1.x += (W1) * (VV).x; a1.y += (W1) * (VV).y;               \
    a1.z += (W1) * (VV).z; a1.w += (W1) * (VV).w;

    #pragma unroll 2
    for (int j = 0; j < N_; j += 4) {
        const float4 w0 = *(const float4*)(wr0 + j);
        const float4 w1 = *(const float4*)(wr1 + j);
        const float4 vv0 = *(const float4*)(vb + (size_t)(j + 0) * D_);
        const float4 vv1 = *(const float4*)(vb + (size_t)(j + 1) * D_);
        const float4 vv2 = *(const float4*)(vb + (size_t)(j + 2) * D_);
        const float4 vv3 = *(const float4*)(vb + (size_t)(j + 3) * D_);
        PV_STEP(w0.x, w1.x, vv0)
        PV_STEP(w0.y, w1.y, vv1)
        PV_STEP(w0.z, w1.z, vv2)
        PV_STEP(w0.w, w1.w, vv3)
    }
#undef PV_STEP

    float* op = out + ((size_t)(b * N_ + i0 + 2 * rp)) * D_ + dq * 4;
    *(float4*)op        = a0;
    *(float4*)(op + D_) = a1;
}

// ---------- Fallback (round-1 kernel, used if ws too small) ----------
__global__ __launch_bounds__(256, 2)
void manh_attn_legacy(const float* __restrict__ q,
                      const float* __restrict__ k,
                      const float* __restrict__ v,
                      float* __restrict__ out)
{
    __shared__ float s_mat[4][N_];
    const int t   = threadIdx.x;
    const int bid = blockIdx.x;
    const int b   = bid >> 6;
    const int i0  = (bid & 63) * 4;

    const float* __restrict__ krow  = k + ((size_t)(b * N_ + t)) * D_;
    const float* __restrict__ qbase = q + ((size_t)(b * N_ + i0)) * D_;

    float acc0 = 0.f, acc1 = 0.f, acc2 = 0.f, acc3 = 0.f;
    #pragma unroll 4
    for (int d = 0; d < D_; d += 4) {
        const float4 kv = *(const float4*)(krow + d);
        const float4 q0 = *(const float4*)(qbase + d);
        const float4 q1 = *(const float4*)(qbase + D_ + d);
        const float4 q2 = *(const float4*)(qbase + 2 * D_ + d);
        const float4 q3 = *(const float4*)(qbase + 3 * D_ + d);
        acc0 += (fabsf(q0.x - kv.x) + fabsf(q0.y - kv.y)) + (fabsf(q0.z - kv.z) + fabsf(q0.w - kv.w));
        acc1 += (fabsf(q1.x - kv.x) + fabsf(q1.y - kv.y)) + (fabsf(q1.z - kv.z) + fabsf(q1.w - kv.w));
        acc2 += (fabsf(q2.x - kv.x) + fabsf(q2.y - kv.y)) + (fabsf(q2.z - kv.z) + fabsf(q2.w - kv.w));
        acc3 += (fabsf(q3.x - kv.x) + fabsf(q3.y - kv.y)) + (fabsf(q3.z - kv.z) + fabsf(q3.w - kv.w));
    }
    s_mat[0][t] = -acc0; s_mat[1][t] = -acc1; s_mat[2][t] = -acc2; s_mat[3][t] = -acc3;
    __syncthreads();
    {
        const int w = t >> 6;
        const int l = t & 63;
        float v0 = s_mat[w][l], v1 = s_mat[w][l + 64], v2 = s_mat[w][l + 128], v3 = s_mat[w][l + 192];
        float m = fmaxf(fmaxf(v0, v1), fmaxf(v2, v3));
        #pragma unroll
        for (int off = 32; off; off >>= 1) m = fmaxf(m, __shfl_xor(m, off));
        const float c = 1.4426950408889634f;
        float e0 = exp2f((v0 - m) * c), e1 = exp2f((v1 - m) * c);
        float e2 = exp2f((v2 - m) * c), e3 = exp2f((v3 - m) * c);
        float s = (e0 + e1) + (e2 + e3);
        #pragma unroll
        for (int off = 32; off; off >>= 1) s += __shfl_xor(s, off);
        const float r = 1.0f / s;
        s_mat[w][l] = e0 * r; s_mat[w][l + 64] = e1 * r;
        s_mat[w][l + 128] = e2 * r; s_mat[w][l + 192] = e3 * r;
    }
    __syncthreads();
    const int ig = t >> 7;
    const int d0 = (t & 127) * 4;
    const float* __restrict__ vbase = v + ((size_t)b * N_) * D_ + d0;
    const float* __restrict__ wr0 = &s_mat[2 * ig][0];
    const float* __restrict__ wr1 = &s_mat[2 * ig + 1][0];
    float4 a0 = make_float4(0.f, 0.f, 0.f, 0.f);
    float4 a1 = make_float4(0.f, 0.f, 0.f, 0.f);
#define PV_STEP(W0, W1, VV)                                     \
    a0.x += (W0) * (VV).x; a0.y += (W0) * (VV).y;               \
    a0.z += (W0) * (VV).z; a0.w += (W0) * (VV).w;               \
    a1.x += (W1) * (VV).x; a1.y += (W1) * (VV).y;               \
    a1.z += (W1) * (VV).z; a1.w += (W1) * (VV).w;
    #pragma unroll 2
    for (int j = 0; j < N_; j += 4) {
        const float4 w0 = *(const float4*)(wr0 + j);
        const float4 w1 = *(const float4*)(wr1 + j);
        const float4 vv0 = *(const float4*)(vbase + (size_t)(j + 0) * D_);
        const float4 vv1 = *(const float4*)(vbase + (size_t)(j + 1) * D_);
        const float4 vv2 = *(const float4*)(vbase + (size_t)(j + 2) * D_);
        const float4 vv3 = *(const float4*)(vbase + (size_t)(j + 3) * D_);
        PV_STEP(w0.x, w1.x, vv0)
        PV_STEP(w0.y, w1.y, vv1)
        PV_STEP(w0.z, w1.z, vv2)
        PV_STEP(w0.w, w1.w, vv3)
    }
#undef PV_STEP
    float* op = out + ((size_t)(b * N_ + i0 + 2 * ig)) * D_ + d0;
    *(float4*)op        = a0;
    *(float4*)(op + D_) = a1;
}

extern "C" void kernel_launch(void* const* d_in, const int* in_sizes, int n_in,
                              void* d_out, int out_size, void* d_ws, size_t ws_size,
                              hipStream_t stream)
{
    const float* q = (const float*)d_in[0];
    const float* k = (const float*)d_in[1];
    const float* v = (const float*)d_in[2];
    float* out = (float*)d_out;

    const size_t kT_bytes = (size_t)B_ * N_ * D_ * sizeof(float);
    if (ws_size >= kT_bytes) {
        float* kT = (float*)d_ws;
        transpose_k<<<dim3(D_ / 32, N_ / 32, B_), dim3(32, 8), 0, stream>>>(k, kT);
        manh_attn_v4<<<dim3(B_ * (N_ / TI)), dim3(512), 0, stream>>>(q, kT, v, out);
    } else {
        manh_attn_legacy<<<dim3(B_ * 64), dim3(256), 0, stream>>>(q, k, v, out);
    }
}

// Round 5
// 44.837 us; speedup vs baseline: 18.8454x; 1.1523x over previous
//
#include <hip/hip_runtime.h>

#define B_ 8
#define N_ 256
#define D_ 512
#define TI 4   // query rows per block

// ---------- Kernel 0: transpose k[b][j][d] -> kT[b][d][j] ----------
__global__ __launch_bounds__(256)
void transpose_k(const float* __restrict__ k, float* __restrict__ kT)
{
    __shared__ float tile[32][33];
    const int dt = blockIdx.x * 32;
    const int jt = blockIdx.y * 32;
    const int b  = blockIdx.z;
    const int tx = threadIdx.x;   // 0..31
    const int ty = threadIdx.y;   // 0..7

    const float* __restrict__ src = k  + ((size_t)b * N_) * D_;
    float* __restrict__       dst = kT + ((size_t)b * D_) * N_;

    #pragma unroll
    for (int r = 0; r < 4; ++r) {
        const int jj = ty * 4 + r;
        tile[jj][tx] = src[(size_t)(jt + jj) * D_ + dt + tx];
    }
    __syncthreads();
    #pragma unroll
    for (int r = 0; r < 4; ++r) {
        const int dd = ty * 4 + r;
        dst[(size_t)(dt + dd) * N_ + jt + tx] = tile[tx][dd];
    }
}

// ---------- Main kernel: TI=4, 512 threads (8 waves), grid = 512 ----------
// b = bid & 7 (batch-major XCD mapping), tile = bid >> 3.
// Phase A: wave w owns d-octant (64 d) x all 4 rows.
__global__ __launch_bounds__(512, 4)
void manh_attn_v5(const float* __restrict__ q,
                  const float* __restrict__ kT,
                  const float* __restrict__ v,
                  float* __restrict__ out)
{
    __shared__ float s_q[TI * D_];       // 8 KB
    __shared__ float s_part[8 * 1024];   // 32 KB: 8 waves x 4 rows x 256 j
    __shared__ float s_w[TI * N_];       // 4 KB

    const int t  = threadIdx.x;
    const int b  = blockIdx.x & 7;          // batch -> XCD locality
    const int i0 = (blockIdx.x >> 3) * TI;  // 0..63 tiles

    // ---- stage q tile (4 rows x 512) into LDS, one float4 per thread ----
    {
        const float* __restrict__ qsrc = q + ((size_t)(b * N_ + i0)) * D_;
        *(float4*)&s_q[4 * t] = *(const float4*)(qsrc + 4 * t);
    }
    __syncthreads();

    const int lane = t & 63;
    const int w    = t >> 6;       // 0..7 = d-octant
    const int dlo  = w * 64;

    // ---- Phase A: partial L1 distances (acc = 16 VGPR) ----
    float4 acc0 = make_float4(0.f,0.f,0.f,0.f);
    float4 acc1 = make_float4(0.f,0.f,0.f,0.f);
    float4 acc2 = make_float4(0.f,0.f,0.f,0.f);
    float4 acc3 = make_float4(0.f,0.f,0.f,0.f);

    const float* __restrict__ kbase =
        kT + (size_t)b * D_ * N_ + (size_t)dlo * N_ + lane * 4;
    const float* __restrict__ qrow0 = &s_q[0 * D_ + dlo];
    const float* __restrict__ qrow1 = &s_q[1 * D_ + dlo];
    const float* __restrict__ qrow2 = &s_q[2 * D_ + dlo];
    const float* __restrict__ qrow3 = &s_q[3 * D_ + dlo];

#define ACC_ROW(A, QP)                                                         \
    {                                                                          \
        const float4 q4 = *(const float4*)((QP) + dd);                         \
        A.x += (fabsf(q4.x - k0.x) + fabsf(q4.y - k1.x)) +                     \
               (fabsf(q4.z - k2.x) + fabsf(q4.w - k3.x));                      \
        A.y += (fabsf(q4.x - k0.y) + fabsf(q4.y - k1.y)) +                     \
               (fabsf(q4.z - k2.y) + fabsf(q4.w - k3.y));                      \
        A.z += (fabsf(q4.x - k0.z) + fabsf(q4.y - k1.z)) +                     \
               (fabsf(q4.z - k2.z) + fabsf(q4.w - k3.z));                      \
        A.w += (fabsf(q4.x - k0.w) + fabsf(q4.y - k1.w)) +                     \
               (fabsf(q4.z - k2.w) + fabsf(q4.w - k3.w));                      \
    }

    #pragma unroll 4
    for (int dd = 0; dd < 64; dd += 4) {
        const float* kp = kbase + (size_t)dd * N_;
        const float4 k0 = *(const float4*)(kp);
        const float4 k1 = *(const float4*)(kp + N_);
        const float4 k2 = *(const float4*)(kp + 2 * N_);
        const float4 k3 = *(const float4*)(kp + 3 * N_);
        ACC_ROW(acc0, qrow0)
        ACC_ROW(acc1, qrow1)
        ACC_ROW(acc2, qrow2)
        ACC_ROW(acc3, qrow3)
    }
#undef ACC_ROW

    // ---- dump partials (one shot) ----
    *(float4*)&s_part[w * 1024 +   0 + lane * 4] = acc0;
    *(float4*)&s_part[w * 1024 + 256 + lane * 4] = acc1;
    *(float4*)&s_part[w * 1024 + 512 + lane * 4] = acc2;
    *(float4*)&s_part[w * 1024 + 768 + lane * 4] = acc3;
    __syncthreads();

    // ---- reduce 8 d-octants -> scores (1024 elems, 2 per thread) ----
    #pragma unroll
    for (int i = 0; i < 2; ++i) {
        const int e = t + 512 * i;      // 0..1023
        const int r = e >> 8;           // 0..3
        const int j = e & 255;
        const int sl = r * 256 + j;
        const float s = ((s_part[0 * 1024 + sl] + s_part[1 * 1024 + sl]) +
                         (s_part[2 * 1024 + sl] + s_part[3 * 1024 + sl])) +
                        ((s_part[4 * 1024 + sl] + s_part[5 * 1024 + sl]) +
                         (s_part[6 * 1024 + sl] + s_part[7 * 1024 + sl]));
        s_w[r * N_ + j] = -s;
    }
    __syncthreads();

    // ---- softmax: waves 0..3 handle rows 0..3 ----
    if (w < TI) {
        float* row = &s_w[w * N_];
        float v0 = row[lane];
        float v1 = row[lane + 64];
        float v2 = row[lane + 128];
        float v3 = row[lane + 192];
        float m = fmaxf(fmaxf(v0, v1), fmaxf(v2, v3));
        #pragma unroll
        for (int off = 32; off; off >>= 1) m = fmaxf(m, __shfl_xor(m, off));
        const float c = 1.4426950408889634f;
        float e0 = exp2f((v0 - m) * c);
        float e1 = exp2f((v1 - m) * c);
        float e2 = exp2f((v2 - m) * c);
        float e3 = exp2f((v3 - m) * c);
        float s = (e0 + e1) + (e2 + e3);
        #pragma unroll
        for (int off = 32; off; off >>= 1) s += __shfl_xor(s, off);
        const float r = 1.0f / s;
        row[lane]       = e0 * r;
        row[lane + 64]  = e1 * r;
        row[lane + 128] = e2 * r;
        row[lane + 192] = e3 * r;
    }
    __syncthreads();

    // ---- Phase C: out = attn @ v ----
    // thread: d-quad dq = t&127, row-pair rp = (t>>7)&1, j-half jh = t>>8
    const int dq = t & 127;
    const int rp = (t >> 7) & 1;
    const int jh = t >> 8;
    const float* __restrict__ vb  = v + (size_t)b * N_ * D_ + dq * 4;
    const float* __restrict__ wr0 = &s_w[(2 * rp) * N_];
    const float* __restrict__ wr1 = &s_w[(2 * rp + 1) * N_];

    float4 a0 = make_float4(0.f,0.f,0.f,0.f);
    float4 a1 = make_float4(0.f,0.f,0.f,0.f);

#define PV_STEP(W0, W1, VV)                                     \
    a0.x += (W0) * (VV).x; a0.y += (W0) * (VV).y;               \
    a0.z += (W0) * (VV).z; a0.w += (W0) * (VV).w;               \
    a1.x += (W1) * (VV).x; a1.y += (W1) * (VV).y;               \
    a1.z += (W1) * (VV).z; a1.w += (W1) * (VV).w;

    const int jbase = jh * 128;
    #pragma unroll 2
    for (int jo = 0; jo < 128; jo += 4) {
        const int j = jbase + jo;
        const float4 w0 = *(const float4*)(wr0 + j);
        const float4 w1 = *(const float4*)(wr1 + j);
        const float4 vv0 = *(const float4*)(vb + (size_t)(j + 0) * D_);
        const float4 vv1 = *(const float4*)(vb + (size_t)(j + 1) * D_);
        const float4 vv2 = *(const float4*)(vb + (size_t)(j + 2) * D_);
        const float4 vv3 = *(const float4*)(vb + (size_t)(j + 3) * D_);
        PV_STEP(w0.x, w1.x, vv0)
        PV_STEP(w0.y, w1.y, vv1)
        PV_STEP(w0.z, w1.z, vv2)
        PV_STEP(w0.w, w1.w, vv3)
    }
#undef PV_STEP

    __syncthreads();   // s_part reuse
    // layout: part[jh][r][d]: jh*2048 + r*512 + d
    *(float4*)&s_part[jh * 2048 + (2 * rp + 0) * 512 + dq * 4] = a0;
    *(float4*)&s_part[jh * 2048 + (2 * rp + 1) * 512 + dq * 4] = a1;
    __syncthreads();

    // ---- final: sum the 2 j-halves, write out (1 float4 per thread) ----
    {
        const int r  = t >> 7;          // 0..3
        const int d4 = (t & 127) * 4;
        const float4 p0 = *(const float4*)&s_part[0 * 2048 + r * 512 + d4];
        const float4 p1 = *(const float4*)&s_part[1 * 2048 + r * 512 + d4];
        float4 s;
        s.x = p0.x + p1.x; s.y = p0.y + p1.y;
        s.z = p0.z + p1.z; s.w = p0.w + p1.w;
        *(float4*)(out + ((size_t)(b * N_ + i0 + r)) * D_ + d4) = s;
    }
}

// ---------- Fallback (round-1 kernel, used if ws too small) ----------
__global__ __launch_bounds__(256, 2)
void manh_attn_legacy(const float* __restrict__ q,
                      const float* __restrict__ k,
                      const float* __restrict__ v,
                      float* __restrict__ out)
{
    __shared__ float s_mat[4][N_];
    const int t   = threadIdx.x;
    const int bid = blockIdx.x;
    const int b   = bid >> 6;
    const int i0  = (bid & 63) * 4;

    const float* __restrict__ krow  = k + ((size_t)(b * N_ + t)) * D_;
    const float* __restrict__ qbase = q + ((size_t)(b * N_ + i0)) * D_;

    float acc0 = 0.f, acc1 = 0.f, acc2 = 0.f, acc3 = 0.f;
    #pragma unroll 4
    for (int d = 0; d < D_; d += 4) {
        const float4 kv = *(const float4*)(krow + d);
        const float4 q0 = *(const float4*)(qbase + d);
        const float4 q1 = *(const float4*)(qbase + D_ + d);
        const float4 q2 = *(const float4*)(qbase + 2 * D_ + d);
        const float4 q3 = *(const float4*)(qbase + 3 * D_ + d);
        acc0 += (fabsf(q0.x - kv.x) + fabsf(q0.y - kv.y)) + (fabsf(q0.z - kv.z) + fabsf(q0.w - kv.w));
        acc1 += (fabsf(q1.x - kv.x) + fabsf(q1.y - kv.y)) + (fabsf(q1.z - kv.z) + fabsf(q1.w - kv.w));
        acc2 += (fabsf(q2.x - kv.x) + fabsf(q2.y - kv.y)) + (fabsf(q2.z - kv.z) + fabsf(q2.w - kv.w));
        acc3 += (fabsf(q3.x - kv.x) + fabsf(q3.y - kv.y)) + (fabsf(q3.z - kv.z) + fabsf(q3.w - kv.w));
    }
    s_mat[0][t] = -acc0; s_mat[1][t] = -acc1; s_mat[2][t] = -acc2; s_mat[3][t] = -acc3;
    __syncthreads();
    {
        const int w = t >> 6;
        const int l = t & 63;
        float v0 = s_mat[w][l], v1 = s_mat[w][l + 64], v2 = s_mat[w][l + 128], v3 = s_mat[w][l + 192];
        float m = fmaxf(fmaxf(v0, v1), fmaxf(v2, v3));
        #pragma unroll
        for (int off = 32; off; off >>= 1) m = fmaxf(m, __shfl_xor(m, off));
        const float c = 1.4426950408889634f;
        float e0 = exp2f((v0 - m) * c), e1 = exp2f((v1 - m) * c);
        float e2 = exp2f((v2 - m) * c), e3 = exp2f((v3 - m) * c);
        float s = (e0 + e1) + (e2 + e3);
        #pragma unroll
        for (int off = 32; off; off >>= 1) s += __shfl_xor(s, off);
        const float r = 1.0f / s;
        s_mat[w][l] = e0 * r; s_mat[w][l + 64] = e1 * r;
        s_mat[w][l + 128] = e2 * r; s_mat[w][l + 192] = e3 * r;
    }
    __syncthreads();
    const int ig = t >> 7;
    const int d0 = (t & 127) * 4;
    const float* __restrict__ vbase = v + ((size_t)b * N_) * D_ + d0;
    const float* __restrict__ wr0 = &s_mat[2 * ig][0];
    const float* __restrict__ wr1 = &s_mat[2 * ig + 1][0];
    float4 a0 = make_float4(0.f, 0.f, 0.f, 0.f);
    float4 a1 = make_float4(0.f, 0.f, 0.f, 0.f);
#define PV_STEP(W0, W1, VV)                                     \
    a0.x += (W0) * (VV).x; a0.y += (W0) * (VV).y;               \
    a0.z += (W0) * (VV).z; a0.w += (W0) * (VV).w;               \
    a1.x += (W1) * (VV).x; a1.y += (W1) * (VV).y;               \
    a1.z += (W1) * (VV).z; a1.w += (W1) * (VV).w;
    #pragma unroll 2
    for (int j = 0; j < N_; j += 4) {
        const float4 w0 = *(const float4*)(wr0 + j);
        const float4 w1 = *(const float4*)(wr1 + j);
        const float4 vv0 = *(const float4*)(vbase + (size_t)(j + 0) * D_);
        const float4 vv1 = *(const float4*)(vbase + (size_t)(j + 1) * D_);
        const float4 vv2 = *(const float4*)(vbase + (size_t)(j + 2) * D_);
        const float4 vv3 = *(const float4*)(vbase + (size_t)(j + 3) * D_);
        PV_STEP(w0.x, w1.x, vv0)
        PV_STEP(w0.y, w1.y, vv1)
        PV_STEP(w0.z, w1.z, vv2)
        PV_STEP(w0.w, w1.w, vv3)
    }
#undef PV_STEP
    float* op = out + ((size_t)(b * N_ + i0 + 2 * ig)) * D_ + d0;
    *(float4*)op        = a0;
    *(float4*)(op + D_) = a1;
}

extern "C" void kernel_launch(void* const* d_in, const int* in_sizes, int n_in,
                              void* d_out, int out_size, void* d_ws, size_t ws_size,
                              hipStream_t stream)
{
    const float* q = (const float*)d_in[0];
    const float* k = (const float*)d_in[1];
    const float* v = (const float*)d_in[2];
    float* out = (float*)d_out;

    const size_t kT_bytes = (size_t)B_ * N_ * D_ * sizeof(float);
    if (ws_size >= kT_bytes) {
        float* kT = (float*)d_ws;
        transpose_k<<<dim3(D_ / 32, N_ / 32, B_), dim3(32, 8), 0, stream>>>(k, kT);
        manh_attn_v5<<<dim3(B_ * (N_ / TI)), dim3(512), 0, stream>>>(q, kT, v, out);
    } else {
        manh_attn_legacy<<<dim3(B_ * 64), dim3(256), 0, stream>>>(q, k, v, out);
    }
}